// Round 6
// baseline (217.347 us; speedup 1.0000x reference)
//
#include <hip/hip_runtime.h>
#include <hip/hip_bf16.h>
#include <math.h>

#define NSTEP 100
#define BATCH 16384
#define MB 16            // samples per wave == MFMA M
#define NBLK (BATCH/MB)  // 1024 single-wave blocks
#define NT 64

#define C_ALPHA 0.05f
#define C_SIGMA 0.2f
#define C_THETA 0.3f
#define C_DT    0.01f
#define C_LOWER 1e-6f
#define C_PEN   100.0f
#define LOG2E   1.4426950408889634f
#define TSCALE  (2.0f * LOG2E)      // tanh(z) = 1 - 2/(exp2(TSCALE*z)+1)
#define CRT ( 0.015f * C_DT * LOG2E)
#define CRW ( 0.1f * LOG2E)
#define CPT (-0.095f * C_DT * LOG2E)
#define CPW (-0.3f * LOG2E)
#define XMUL (1.0f + C_ALPHA * C_DT)

typedef __attribute__((ext_vector_type(8))) short bf16x8;
typedef __attribute__((ext_vector_type(4))) float f32x4;

__device__ __forceinline__ float tanh_pre(float zs) {  // zs = TSCALE*z pre-folded
    float e = __builtin_amdgcn_exp2f(zs);
    return 1.0f - 2.0f * __builtin_amdgcn_rcpf(e + 1.0f);
}
__device__ __forceinline__ unsigned f2bf_u(float f) {  // RNE
    unsigned u = __float_as_uint(f);
    return (u + 0x7FFFu + ((u >> 16) & 1u)) >> 16;
}
__device__ __forceinline__ unsigned pack_bf16(float a, float b) {
    union { __hip_bfloat162 h; unsigned u; } cv;
    cv.h = __float22bfloat162_rn(make_float2(a, b));   // v_cvt_pk_bf16_f32
    return cv.u;
}
// sum across each 16-lane row via DPP row_ror butterfly; all lanes get the sum
__device__ __forceinline__ float dpp_row_sum16(float v) {
    int t;
    t = __builtin_amdgcn_update_dpp(0, __float_as_int(v), 0x128, 0xF, 0xF, true);
    v += __int_as_float(t);
    t = __builtin_amdgcn_update_dpp(0, __float_as_int(v), 0x124, 0xF, 0xF, true);
    v += __int_as_float(t);
    t = __builtin_amdgcn_update_dpp(0, __float_as_int(v), 0x122, 0xF, 0xF, true);
    v += __int_as_float(t);
    t = __builtin_amdgcn_update_dpp(0, __float_as_int(v), 0x121, 0xF, 0xF, true);
    v += __int_as_float(t);
    return v;
}

__global__ __launch_bounds__(NT, 1) void fused_kernel(
        const float* __restrict__ dw, const float* __restrict__ X0,
        const float* __restrict__ R0,
        const float* __restrict__ pW1, const float* __restrict__ pb1,
        const float* __restrict__ pW2, const float* __restrict__ pb2,
        const float* __restrict__ pW3, const float* __restrict__ pb3,
        const float* __restrict__ qW1, const float* __restrict__ qb1,
        const float* __restrict__ qW2, const float* __restrict__ qb2,
        const float* __restrict__ qW3, const float* __restrict__ qb3,
        float* __restrict__ ws, float* __restrict__ out) {
    __shared__ __align__(16) unsigned short sW2T[64 * 72];  // bf16 W2^T [n][k] *TSCALE
    __shared__ __align__(16) float sdw[MB * NSTEP];
    __shared__ __align__(16) float sR[NSTEP * MB];          // R_t, t=1..100 -> [(t-1)*16+s]
    __shared__ float sPf[MB];                               // p_100 per sample

    const int lane = threadIdx.x;          // single wave
    const int b0 = blockIdx.x * MB;
    const int l15 = lane & 15, quad = lane >> 4;

    // ---- stage dw (coalesced float4) and W2^T (bf16, pre-scaled) ----
    {
        const float4* g = (const float4*)(dw + (size_t)b0 * NSTEP);
        float4* s = (float4*)sdw;
        #pragma unroll
        for (int u = lane; u < MB * NSTEP / 4; u += NT) s[u] = g[u];
    }
    #pragma unroll 8
    for (int t = 0; t < 64; t++)
        sW2T[lane * 72 + t] = (unsigned short)f2bf_u(qW2[t * 64 + lane] * TSCALE);
    __syncthreads();

    const float X0v = X0[0], R0s = R0[0];
    const float b3 = qb3[0];

    // ---- p-net: p0, dp0 (one-time shuffle MLP; all lanes get values) ----
    float p0, dp0;
    {
        float pre = fmaf(pW1[64 + lane], X0v, fmaf(pW1[128 + lane], R0s, pb1[lane]));
        float h1 = tanh_pre(TSCALE * pre);
        float d1 = (1.0f - h1 * h1) * pW1[64 + lane];
        float a0 = pb2[lane], a1 = 0.f, a2 = 0.f, a3 = 0.f;
        float e0 = 0.f, e1 = 0.f, e2 = 0.f, e3 = 0.f;
        for (int i2 = 0; i2 < 64; i2 += 4) {
            float w0 = pW2[(i2 + 0) * 64 + lane];
            float w1 = pW2[(i2 + 1) * 64 + lane];
            float w2 = pW2[(i2 + 2) * 64 + lane];
            float w3 = pW2[(i2 + 3) * 64 + lane];
            a0 = fmaf(__shfl(h1, i2 + 0), w0, a0); e0 = fmaf(__shfl(d1, i2 + 0), w0, e0);
            a1 = fmaf(__shfl(h1, i2 + 1), w1, a1); e1 = fmaf(__shfl(d1, i2 + 1), w1, e1);
            a2 = fmaf(__shfl(h1, i2 + 2), w2, a2); e2 = fmaf(__shfl(d1, i2 + 2), w2, e2);
            a3 = fmaf(__shfl(h1, i2 + 3), w3, a3); e3 = fmaf(__shfl(d1, i2 + 3), w3, e3);
        }
        float pre2 = (a0 + a1) + (a2 + a3);
        float dpre2 = (e0 + e1) + (e2 + e3);
        float h2 = tanh_pre(TSCALE * pre2);
        float d2 = (1.0f - h2 * h2) * dpre2;
        float c1 = h2 * pW3[lane], c2 = d2 * pW3[lane];
        #pragma unroll
        for (int o = 1; o < 64; o <<= 1) {
            c1 += __shfl_xor(c1, o);
            c2 += __shfl_xor(c2, o);
        }
        p0 = c1 + pb3[0]; dp0 = c2;
    }

    // ---- pre-phase: R_t, p_t trajectories (x-independent) + out cols 1/3/4 ----
    {
        const int ps = lane >> 2;      // sample
        const int pc = lane & 3;       // 25-step chunk
        float loc = 0.0f;
        #pragma unroll 5
        for (int j = pc * 25; j < pc * 25 + 25; j++) loc += sdw[ps * NSTEP + j];
        float o0 = __shfl(loc, ps * 4 + 0);
        float o1 = __shfl(loc, ps * 4 + 1);
        float o2 = __shfl(loc, ps * 4 + 2);
        float W = 0.0f;
        if (pc > 0) W += o0;
        if (pc > 1) W += o1;
        if (pc > 2) W += o2;
        #pragma unroll 5
        for (int t = pc * 25 + 1; t <= pc * 25 + 25; t++) {
            W += sdw[ps * NSTEP + (t - 1)];
            float ft = (float)t;
            float R = R0s * __builtin_amdgcn_exp2f(fmaf(CRW, W, CRT * ft));
            float pm = p0 * __builtin_amdgcn_exp2f(fmaf(CPW, W, CPT * ft));
            sR[(t - 1) * MB + ps] = R;
            size_t base = ((size_t)t * BATCH + b0 + ps) * 5;
            out[base + 1] = R; out[base + 3] = -pm; out[base + 4] = -dp0;
            if (t == NSTEP) sPf[ps] = pm;
        }
        if (lane < MB) {   // row 0 (col2 pi0 written later)
            size_t base = (size_t)(b0 + lane) * 5;
            out[base] = X0v; out[base + 1] = R0s;
            out[base + 3] = -p0; out[base + 4] = -dp0;
        }
    }
    __syncthreads();

    // ---- resident B fragments + per-lane consts ----
    bf16x8 Bf[4][2];
    #pragma unroll
    for (int nt = 0; nt < 4; nt++) {
        const unsigned short* r = &sW2T[(nt * 16 + l15) * 72 + quad * 8];
        Bf[nt][0] = *(const bf16x8*)r;
        Bf[nt][1] = *(const bf16x8*)(r + 32);
    }
    float tco[16], w1xs[16], w1rs[16], zc[16];
    #pragma unroll
    for (int idx = 0; idx < 16; idx++) {
        int k = (idx < 8) ? (quad * 8 + idx) : (32 + quad * 8 + (idx - 8));
        tco[idx]  = qW1[k] * (2.0f * C_DT * TSCALE);
        w1xs[idx] = qW1[64 + k] * TSCALE;
        w1rs[idx] = qW1[128 + k] * TSCALE;
        zc[idx]   = qb1[k] * TSCALE;       // fi = 0 state
    }
    float b2v[4], w3v[4];
    #pragma unroll
    for (int nt = 0; nt < 4; nt++) {
        b2v[nt] = qb2[nt * 16 + l15] * TSCALE;
        w3v[nt] = qW3[nt * 16 + l15];
    }
    const int bperm_idx = (((l15 >> 2) * 16) + (l15 & 3)) * 4;

    // layer2+3 from A fragments -> pi on all lanes
    auto l23 = [&](const bf16x8& A0, const bf16x8& A1) -> float {
        f32x4 acc0 = {b2v[0], b2v[0], b2v[0], b2v[0]};
        f32x4 acc1 = {b2v[1], b2v[1], b2v[1], b2v[1]};
        f32x4 acc2 = {b2v[2], b2v[2], b2v[2], b2v[2]};
        f32x4 acc3 = {b2v[3], b2v[3], b2v[3], b2v[3]};
        acc0 = __builtin_amdgcn_mfma_f32_16x16x32_bf16(A0, Bf[0][0], acc0, 0, 0, 0);
        acc1 = __builtin_amdgcn_mfma_f32_16x16x32_bf16(A0, Bf[1][0], acc1, 0, 0, 0);
        acc2 = __builtin_amdgcn_mfma_f32_16x16x32_bf16(A0, Bf[2][0], acc2, 0, 0, 0);
        acc3 = __builtin_amdgcn_mfma_f32_16x16x32_bf16(A0, Bf[3][0], acc3, 0, 0, 0);
        acc0 = __builtin_amdgcn_mfma_f32_16x16x32_bf16(A1, Bf[0][1], acc0, 0, 0, 0);
        acc1 = __builtin_amdgcn_mfma_f32_16x16x32_bf16(A1, Bf[1][1], acc1, 0, 0, 0);
        acc2 = __builtin_amdgcn_mfma_f32_16x16x32_bf16(A1, Bf[2][1], acc2, 0, 0, 0);
        acc3 = __builtin_amdgcn_mfma_f32_16x16x32_bf16(A1, Bf[3][1], acc3, 0, 0, 0);
        float th[16];
        #pragma unroll
        for (int r = 0; r < 4; r++) {   // phase bursts for trans pipelining
            th[r]      = tanh_pre(acc0[r]);
            th[4 + r]  = tanh_pre(acc1[r]);
            th[8 + r]  = tanh_pre(acc2[r]);
            th[12 + r] = tanh_pre(acc3[r]);
        }
        f32x4 part;
        #pragma unroll
        for (int r = 0; r < 4; r++) {
            float s = th[r] * w3v[0];
            s = fmaf(th[4 + r],  w3v[1], s);
            s = fmaf(th[8 + r],  w3v[2], s);
            s = fmaf(th[12 + r], w3v[3], s);
            part[r] = dpp_row_sum16(s);
        }
        float sLo = (lane & 1) ? part[1] : part[0];
        float sHi = (lane & 1) ? part[3] : part[2];
        float sel = (lane & 2) ? sHi : sLo;
        int g = __builtin_amdgcn_ds_bpermute(bperm_idx, __float_as_int(sel));
        return __int_as_float(g) + b3;
    };

    // ---- initial pi (t = 0: zc holds fi=0, R = R0s, x = X0v) ----
    float pi;
    {
        union { bf16x8 v; unsigned u[4]; } A0, A1;
        float z[16];
        #pragma unroll
        for (int idx = 0; idx < 16; idx++)
            z[idx] = fmaf(w1rs[idx], R0s, fmaf(w1xs[idx], X0v, zc[idx]));
        float th[16];
        #pragma unroll
        for (int idx = 0; idx < 16; idx++) th[idx] = tanh_pre(z[idx]);
        #pragma unroll
        for (int p = 0; p < 4; p++) {
            A0.u[p] = pack_bf16(th[2 * p], th[2 * p + 1]);
            A1.u[p] = pack_bf16(th[8 + 2 * p], th[9 + 2 * p]);
        }
        pi = l23(A0.v, A1.v);
    }
    if (quad == 0) out[(size_t)(b0 + l15) * 5 + 2] = pi;

    // ---- main scan ----
    float x = X0v, minx = X0v;
    float dw_cur = sdw[l15 * NSTEP];       // dw_0
    float R_cur = sR[l15];                 // R_1
    float* po = out + ((size_t)BATCH + b0 + l15) * 5;   // row 1, this lane's sample

    #pragma unroll 1
    for (int i = 0; i < NSTEP - 1; i++) {
        // prefetch next-iteration operands (off-path)
        float dw_nx = sdw[l15 * NSTEP + i + 1];
        float R_nx  = sR[(i + 1) * MB + l15];
        // off-path prep: zc += tco (fi = i+1); rz = w1r*R + zc; xa; cdw
        float rz[16];
        #pragma unroll
        for (int idx = 0; idx < 16; idx++) {
            zc[idx] += tco[idx];
            rz[idx] = fmaf(w1rs[idx], R_cur, zc[idx]);
        }
        float xa = x * XMUL;
        float cdw = fmaf(C_SIGMA, dw_cur, C_SIGMA * C_THETA * C_DT);
        // path: x update
        x = fmaf(pi, cdw, xa);
        minx = fminf(minx, x);
        if (quad == 0) po[0] = x;
        // layer 1
        float z[16];
        #pragma unroll
        for (int idx = 0; idx < 16; idx++) z[idx] = fmaf(w1xs[idx], x, rz[idx]);
        float th[16];
        #pragma unroll
        for (int idx = 0; idx < 16; idx++) th[idx] = tanh_pre(z[idx]);
        union { bf16x8 v; unsigned u[4]; } A0, A1;
        #pragma unroll
        for (int p = 0; p < 4; p++) {
            A0.u[p] = pack_bf16(th[2 * p], th[2 * p + 1]);
            A1.u[p] = pack_bf16(th[8 + 2 * p], th[9 + 2 * p]);
        }
        float pin = l23(A0.v, A1.v);
        if (quad == 0) po[2] = pin;
        pi = pin;
        dw_cur = dw_nx; R_cur = R_nx;
        po += (size_t)BATCH * 5;
    }

    // ---- final step i=99 (pi not updated) + losses ----
    {
        float xa = x * XMUL;
        float cdw = fmaf(C_SIGMA, dw_cur, C_SIGMA * C_THETA * C_DT);
        x = fmaf(pi, cdw, xa);
        minx = fminf(minx, x);
        float Rf = R_cur;                  // R_100 (prefetched at i=98)
        float pf = sPf[l15];
        if (quad == 0) { po[0] = x; po[2] = pi; }
        float xc = fmaxf(x, C_LOWER);
        float ux = Rf * rsqrtf(xc);           // R * xc^(gamma-1), gamma=0.5
        float uval = 2.0f * Rf * sqrtf(xc);   // R * xc^gamma / gamma
        float d = fmaxf(C_LOWER - minx, 0.0f);
        float pen = C_PEN * d * d;
        float t1 = pf + ux;
        float v1 = dpp_row_sum16(t1 * t1 + pen);
        float v2 = dpp_row_sum16(-uval + pen);
        if (lane == 0) {
            atomicAdd(&ws[3], v1);
            atomicAdd(&ws[4], v2);
            __threadfence();
            int old = atomicAdd((int*)(ws + 5), 1);
            if (old == NBLK - 1) {   // last block finalizes losses
                float lp = atomicAdd(&ws[3], 0.0f) * (1.0f / (float)BATCH);
                float lq = atomicAdd(&ws[4], 0.0f) * (1.0f / (float)BATCH);
                out[(size_t)(NSTEP + 1) * BATCH * 5] = lp;
                out[(size_t)(NSTEP + 1) * BATCH * 5 + 1] = lp + lq;
            }
        }
    }
}

extern "C" void kernel_launch(void* const* d_in, const int* in_sizes, int n_in,
                              void* d_out, int out_size, void* d_ws, size_t ws_size,
                              hipStream_t stream) {
    const float* dw  = (const float*)d_in[0];
    const float* X0  = (const float*)d_in[1];
    const float* R0  = (const float*)d_in[2];
    const float* pW1 = (const float*)d_in[3];
    const float* pb1 = (const float*)d_in[4];
    const float* pW2 = (const float*)d_in[5];
    const float* pb2 = (const float*)d_in[6];
    const float* pW3 = (const float*)d_in[7];
    const float* pb3 = (const float*)d_in[8];
    const float* qW1 = (const float*)d_in[9];
    const float* qb1 = (const float*)d_in[10];
    const float* qW2 = (const float*)d_in[11];
    const float* qb2 = (const float*)d_in[12];
    const float* qW3 = (const float*)d_in[13];
    const float* qb3 = (const float*)d_in[14];
    float* out = (float*)d_out;
    float* ws  = (float*)d_ws;

    hipMemsetAsync(d_ws, 0, 64, stream);   // zero loss accumulators + block counter
    fused_kernel<<<NBLK, NT, 0, stream>>>(dw, X0, R0, pW1, pb1, pW2, pb2, pW3, pb3,
                                          qW1, qb1, qW2, qb2, qW3, qb3, ws, out);
}